// Round 4
// baseline (115.459 us; speedup 1.0000x reference)
//
#include <hip/hip_runtime.h>

typedef __attribute__((ext_vector_type(8))) short short8;     // 8 bf16 = 4 VGPRs
typedef __attribute__((ext_vector_type(4))) float f32x4;
typedef __attribute__((ext_vector_type(4))) unsigned short u16x4;

#define NVEC 65536
#define DDIM 64
#define KCODES 1024
#define NELEM 4194304   // NVEC * DDIM
#define VPB 64          // vectors per block -> grid 1024 = 4 blocks/CU

// fp32 -> bf16 round-to-nearest-even (no NaN/inf in this problem)
static __device__ inline unsigned short f2bf(float f) {
  unsigned u = __builtin_bit_cast(unsigned, f);
  return (unsigned short)((u + 0x7FFFu + ((u >> 16) & 1u)) >> 16);
}
static __device__ inline float bf2f(unsigned short b) {
  return __builtin_bit_cast(float, (unsigned)b << 16);
}

// ---- kernel 1: cb -> bf16, en1[k] = 1 + ||e_bf||^2, zero loss cell ---------
__global__ __launch_bounds__(256) void vq_prep(const float* __restrict__ cb,
                                               unsigned short* __restrict__ cb_bf,
                                               float* __restrict__ en1,
                                               float* __restrict__ out) {
  int t = blockIdx.x * 256 + threadIdx.x;
  float4 v = ((const float4*)cb)[t];
  unsigned short b0 = f2bf(v.x), b1 = f2bf(v.y), b2 = f2bf(v.z), b3 = f2bf(v.w);
  u16x4 pk = {b0, b1, b2, b3};
  *(u16x4*)(cb_bf + (size_t)t * 4) = pk;
  float e0 = bf2f(b0), e1 = bf2f(b1), e2 = bf2f(b2), e3 = bf2f(b3);
  float s = (e0 * e0 + e1 * e1) + (e2 * e2 + e3 * e3);
  s += __shfl_xor(s, 1, 64);
  s += __shfl_xor(s, 2, 64);
  s += __shfl_xor(s, 4, 64);
  s += __shfl_xor(s, 8, 64);
  if ((t & 15) == 0) en1[t >> 4] = 1.0f + s;  // +1 keeps scores in [0.8,1.2]>0
  if (t == 0) out[NELEM] = 0.f;               // loss accumulator
}

// ---- kernel 2: MFMA argmin + gather + output + loss ------------------------
// Block = 4 waves, 64 vectors. Wave w: vector half (w&1)*32 (2 m-tiles),
// code half (w>>1)*512. 4 blocks/CU (launch_bounds(256,4), grid 1024) gives
// 4 waves/SIMD; unroll-4 K-loop keeps 8 B-loads in flight -> L2 latency
// (~230 cyc) hidden by ~320 cyc of other-wave compute. B-frags direct
// global->reg (cb_bf 128 KB, L2-resident); no K-loop barriers. Argmin as
// packed u32 key (p>0 -> bitcast monotone) | 10-bit idx; v_min_u32 update.
__global__ __launch_bounds__(256, 4) void vq_main(
    const float* __restrict__ x, const float* __restrict__ cb,
    const unsigned short* __restrict__ cb_bf, const float* __restrict__ en1,
    float* __restrict__ out) {
  __shared__ float en_s[KCODES];   // 4 KB: 1+||e||^2 per code
  __shared__ unsigned skey[VPB];
  __shared__ float xn[VPB];

  const int tid = threadIdx.x;
  const int wid = tid >> 6;
  const int L = tid & 63;
  const int c16 = L & 15;
  const int q = L >> 4;
  const int vblk = blockIdx.x * VPB;
  const int mbase = (wid & 1) * 32;   // wave's 32-vector half
  const int cbase = (wid >> 1) * 512; // wave's code half

  // stage en1 -> LDS (one float4/thread); init combine keys
  ((float4*)en_s)[tid] = ((const float4*)en1)[tid];
  if (tid < VPB) skey[tid] = 0xFFFFFFFFu;

  // A-frags direct from global: a[mt][h] lane L -> vector mbase+mt*16+c16,
  // d = h*32 + q*8. Also per-vector ||x_bf||^2 via in-wave reduce.
  short8 a[2][2];
#pragma unroll
  for (int mt = 0; mt < 2; ++mt) {
    const float* xv = x + (size_t)(vblk + mbase + mt * 16 + c16) * DDIM + q * 8;
    float4 u0 = *(const float4*)(xv);
    float4 u1 = *(const float4*)(xv + 4);
    float4 u2 = *(const float4*)(xv + 32);
    float4 u3 = *(const float4*)(xv + 36);
    unsigned short h0 = f2bf(u0.x), h1 = f2bf(u0.y), h2 = f2bf(u0.z), h3 = f2bf(u0.w);
    unsigned short h4 = f2bf(u1.x), h5 = f2bf(u1.y), h6 = f2bf(u1.z), h7 = f2bf(u1.w);
    unsigned short g0 = f2bf(u2.x), g1 = f2bf(u2.y), g2 = f2bf(u2.z), g3 = f2bf(u2.w);
    unsigned short g4 = f2bf(u3.x), g5 = f2bf(u3.y), g6 = f2bf(u3.z), g7 = f2bf(u3.w);
    short8 A0 = {(short)h0, (short)h1, (short)h2, (short)h3,
                 (short)h4, (short)h5, (short)h6, (short)h7};
    short8 A1 = {(short)g0, (short)g1, (short)g2, (short)g3,
                 (short)g4, (short)g5, (short)g6, (short)g7};
    a[mt][0] = A0;
    a[mt][1] = A1;
    float s0 = bf2f(h0), s1 = bf2f(h1), s2 = bf2f(h2), s3 = bf2f(h3);
    float s4 = bf2f(h4), s5 = bf2f(h5), s6 = bf2f(h6), s7 = bf2f(h7);
    float t0 = bf2f(g0), t1 = bf2f(g1), t2 = bf2f(g2), t3 = bf2f(g3);
    float t4 = bf2f(g4), t5 = bf2f(g5), t6 = bf2f(g6), t7 = bf2f(g7);
    float xs = ((s0 * s0 + s1 * s1) + (s2 * s2 + s3 * s3)) +
               ((s4 * s4 + s5 * s5) + (s6 * s6 + s7 * s7)) +
               ((t0 * t0 + t1 * t1) + (t2 * t2 + t3 * t3)) +
               ((t4 * t4 + t5 * t5) + (t6 * t6 + t7 * t7));
    xs += __shfl_xor(xs, 16, 64);  // reduce over q (d-chunks)
    xs += __shfl_xor(xs, 32, 64);
    if (wid < 2 && L < 16) xn[mbase + mt * 16 + L] = xs;  // waves 2,3 duplicate
  }
  __syncthreads();  // skey/xn/en_s ready

  unsigned bestk[2][4];
#pragma unroll
  for (int m = 0; m < 2; ++m)
#pragma unroll
    for (int r = 0; r < 4; ++r) bestk[m][r] = 0xFFFFFFFFu;

  const unsigned short* bptr = cb_bf + (size_t)(cbase + c16) * DDIM + q * 8;
#pragma unroll 4
  for (int nt = 0; nt < 32; ++nt) {
    short8 b0 = *(const short8*)(bptr + nt * 16 * DDIM);
    short8 b1 = *(const short8*)(bptr + nt * 16 * DDIM + 32);
    float env = en_s[cbase + nt * 16 + c16];
    unsigned kidx = (unsigned)(cbase + nt * 16 + c16);
#pragma unroll
    for (int m = 0; m < 2; ++m) {
      f32x4 z = {0.f, 0.f, 0.f, 0.f};
      f32x4 acc = __builtin_amdgcn_mfma_f32_16x16x32_bf16(a[m][0], b0, z, 0, 0, 0);
      acc = __builtin_amdgcn_mfma_f32_16x16x32_bf16(a[m][1], b1, acc, 0, 0, 0);
#pragma unroll
      for (int r = 0; r < 4; ++r) {
        // p = (1+||e||^2) - 2 x.e  in [0.8,1.2] -> bitcast monotone
        float p = fmaf(-2.f, acc[r], env);
        unsigned key = (__builtin_bit_cast(unsigned, p) & 0xFFFFFC00u) | kidx;
        bestk[m][r] = key < bestk[m][r] ? key : bestk[m][r];
      }
    }
  }

  // fold 16 columns (lanes differing in c16), then cross-wave combine
#pragma unroll
  for (int m = 0; m < 2; ++m)
#pragma unroll
    for (int r = 0; r < 4; ++r) {
      unsigned k = bestk[m][r];
      k = min(k, (unsigned)__shfl_xor((int)k, 1, 64));
      k = min(k, (unsigned)__shfl_xor((int)k, 2, 64));
      k = min(k, (unsigned)__shfl_xor((int)k, 4, 64));
      k = min(k, (unsigned)__shfl_xor((int)k, 8, 64));
      if (c16 == 0) atomicMin(&skey[mbase + m * 16 + q * 4 + r], k);
    }
  __syncthreads();

  // gather fp32 codebook row -> output (x + (e-x) == e exactly in fp32 here)
#pragma unroll
  for (int i = 0; i < 4; ++i) {
    int f = i * 256 + tid;  // float4 id in block tile [0,1024)
    int v = f >> 4, d4 = f & 15;
    int id = (int)(skey[v] & 1023u);
    ((float4*)out)[(size_t)vblk * 16 + f] = ((const float4*)cb)[(size_t)id * 16 + d4];
  }

  // loss: dist^2 = (p_trunc - 1) + ||x_bf||^2 ; one atomic per block
  if (wid == 0) {
    unsigned k = skey[L];
    float pt = __builtin_bit_cast(float, k & 0xFFFFFC00u);
    float pl = (pt - 1.0f) + xn[L];
#pragma unroll
    for (int off = 32; off >= 1; off >>= 1) pl += __shfl_down(pl, off, 64);
    if (L == 0) atomicAdd(out + NELEM, pl * (1.25f / (float)NELEM));
  }
}

extern "C" void kernel_launch(void* const* d_in, const int* in_sizes, int n_in,
                              void* d_out, int out_size, void* d_ws,
                              size_t ws_size, hipStream_t stream) {
  const float* x = (const float*)d_in[0];   // [65536, 64]
  const float* cb = (const float*)d_in[1];  // [1024, 64]
  float* out = (float*)d_out;               // [NELEM] quantized + [1] loss
  char* ws = (char*)d_ws;
  unsigned short* cb_bf = (unsigned short*)ws;  // 128 KB
  float* en1 = (float*)(ws + 131072);           // 4 KB

  vq_prep<<<64, 256, 0, stream>>>(cb, cb_bf, en1, out);
  vq_main<<<NVEC / VPB, 256, 0, stream>>>(x, cb, cb_bf, en1, out);
}